// Round 1
// baseline (548.624 us; speedup 1.0000x reference)
//
#include <hip/hip_runtime.h>

#define B_SZ 1024
#define S_SZ 200
#define D_SZ 64
#define NI_SZ 4
#define E_SZ 256

// ---------------- K1a: user profile = 0.25*(U[uid]+G[gender]+A[age]+O[occup]) ----------------
__global__ __launch_bounds__(64) void profile_kernel(
    const int* __restrict__ uid, const int* __restrict__ age,
    const int* __restrict__ gender, const int* __restrict__ occup,
    const float* __restrict__ U, const float* __restrict__ AT,
    const float* __restrict__ GT, const float* __restrict__ OT,
    float* __restrict__ prof)
{
  const int b = blockIdx.x;
  const int d = threadIdx.x;
  float v = U[(size_t)uid[b]   * D_SZ + d]
          + GT[(size_t)gender[b] * D_SZ + d]
          + AT[(size_t)age[b]    * D_SZ + d]
          + OT[(size_t)occup[b]  * D_SZ + d];
  prof[b * D_SZ + d] = 0.25f * v;
}

// ---------------- K1b: item_his = mid_emb[mid_his] * mask ----------------
__global__ __launch_bounds__(256) void gather_kernel(
    const int* __restrict__ mid_his, const float* __restrict__ mask,
    const float* __restrict__ memb, float* __restrict__ item)
{
  int idx = blockIdx.x * 256 + threadIdx.x;   // float4 units
  if (idx >= B_SZ * S_SZ * 16) return;
  const int d4 = (idx & 15) * 4;
  const int bs = idx >> 4;
  const float4 v = *(const float4*)(memb + (size_t)mid_his[bs] * D_SZ + d4);
  const float m = mask[bs];
  *(float4*)(item + (size_t)bs * D_SZ + d4) = make_float4(v.x*m, v.y*m, v.z*m, v.w*m);
}

// ---------------- K2: adj[b,i,j] = sigmoid(sum_d H[i,d]*P[d]*H[j,d]) * m_i * m_j ----------------
// k-major LDS layout: HsT[k][i] so per-lane 8-contiguous-float reads are ~2-way bank free.
__global__ __launch_bounds__(256) void adj_kernel(
    const float* __restrict__ item, const float* __restrict__ prof,
    const float* __restrict__ mask, float* __restrict__ adj)
{
  const int b = blockIdx.x;
  __shared__ float HsT[D_SZ][208];   // [k][i], i<200, pad 208 (53.2 KB -> 2 blocks/CU)
  __shared__ float Ps[D_SZ];
  __shared__ float Ms[S_SZ];
  const float* Hg = item + (size_t)b * S_SZ * D_SZ;
  for (int idx = threadIdx.x; idx < S_SZ * 16; idx += 256) {
    const int i = idx >> 4, k4 = (idx & 15) * 4;
    const float4 v = *(const float4*)(Hg + i * D_SZ + k4);
    HsT[k4+0][i] = v.x; HsT[k4+1][i] = v.y;
    HsT[k4+2][i] = v.z; HsT[k4+3][i] = v.w;
  }
  if (threadIdx.x < D_SZ) Ps[threadIdx.x] = prof[b * D_SZ + threadIdx.x];
  if (threadIdx.x < S_SZ) Ms[threadIdx.x] = mask[b * S_SZ + threadIdx.x];
  __syncthreads();

  float* outb = adj + (size_t)b * S_SZ * S_SZ;
  for (int tile = threadIdx.x; tile < 625; tile += 256) {   // 25x25 tiles of 8x8
    const int ti = tile / 25, tj = tile % 25;
    const int i0 = ti * 8, j0 = tj * 8;
    float acc[8][8];
    #pragma unroll
    for (int ii = 0; ii < 8; ii++)
      #pragma unroll
      for (int jj = 0; jj < 8; jj++) acc[ii][jj] = 0.f;

    #pragma unroll 4
    for (int k = 0; k < D_SZ; k++) {
      const float pk = Ps[k];
      const float4 a0 = *(const float4*)&HsT[k][i0];
      const float4 a1 = *(const float4*)&HsT[k][i0 + 4];
      const float4 b0 = *(const float4*)&HsT[k][j0];
      const float4 b1 = *(const float4*)&HsT[k][j0 + 4];
      const float av[8] = {a0.x*pk, a0.y*pk, a0.z*pk, a0.w*pk,
                           a1.x*pk, a1.y*pk, a1.z*pk, a1.w*pk};
      const float bv[8] = {b0.x, b0.y, b0.z, b0.w, b1.x, b1.y, b1.z, b1.w};
      #pragma unroll
      for (int ii = 0; ii < 8; ii++)
        #pragma unroll
        for (int jj = 0; jj < 8; jj++)
          acc[ii][jj] = fmaf(av[ii], bv[jj], acc[ii][jj]);
    }
    #pragma unroll
    for (int ii = 0; ii < 8; ii++) {
      const float mi = Ms[i0 + ii];
      float r[8];
      #pragma unroll
      for (int jj = 0; jj < 8; jj++) {
        const float sg = 1.f / (1.f + __expf(-acc[ii][jj]));
        r[jj] = sg * mi * Ms[j0 + jj];
      }
      *(float4*)(outb + (i0+ii) * S_SZ + j0)     = make_float4(r[0], r[1], r[2], r[3]);
      *(float4*)(outb + (i0+ii) * S_SZ + j0 + 4) = make_float4(r[4], r[5], r[6], r[7]);
    }
  }
}

// ---------------- K3: hat[b,kc,s,d] = sum_k H[b,s,k] * W[s, kc*64+d, k] ----------------
// Block: one s, 64 b-rows, 128 e-cols. k-major LDS. Thread tile 4b x 8e.
__global__ __launch_bounds__(256) void hat_kernel(
    const float* __restrict__ item, const float* __restrict__ wcap,
    float* __restrict__ hat)
{
  const int s  = blockIdx.x;
  const int b0 = blockIdx.y * 64;
  const int e0 = blockIdx.z * 128;
  __shared__ float WsT[D_SZ][136];  // [k][e], e<128
  __shared__ float HsT[D_SZ][72];   // [k][b], b<64
  for (int idx = threadIdx.x; idx < 128 * 16; idx += 256) {
    const int e = idx >> 4, k4 = (idx & 15) * 4;
    const float4 v = *(const float4*)(wcap + ((size_t)s * E_SZ + e0 + e) * D_SZ + k4);
    WsT[k4+0][e] = v.x; WsT[k4+1][e] = v.y; WsT[k4+2][e] = v.z; WsT[k4+3][e] = v.w;
  }
  for (int idx = threadIdx.x; idx < 64 * 16; idx += 256) {
    const int r = idx >> 4, k4 = (idx & 15) * 4;
    const float4 v = *(const float4*)(item + ((size_t)(b0 + r) * S_SZ + s) * D_SZ + k4);
    HsT[k4+0][r] = v.x; HsT[k4+1][r] = v.y; HsT[k4+2][r] = v.z; HsT[k4+3][r] = v.w;
  }
  __syncthreads();

  const int ti = threadIdx.x >> 4;   // 0..15 -> 4 b-rows
  const int tj = threadIdx.x & 15;   // 0..15 -> 8 e-cols
  const int bt = ti * 4, et = tj * 8;
  float acc[4][8];
  #pragma unroll
  for (int ii = 0; ii < 4; ii++)
    #pragma unroll
    for (int jj = 0; jj < 8; jj++) acc[ii][jj] = 0.f;

  #pragma unroll 4
  for (int k = 0; k < D_SZ; k++) {
    const float4 a  = *(const float4*)&HsT[k][bt];
    const float4 w0 = *(const float4*)&WsT[k][et];
    const float4 w1 = *(const float4*)&WsT[k][et + 4];
    const float av[4] = {a.x, a.y, a.z, a.w};
    const float wv[8] = {w0.x, w0.y, w0.z, w0.w, w1.x, w1.y, w1.z, w1.w};
    #pragma unroll
    for (int ii = 0; ii < 4; ii++)
      #pragma unroll
      for (int jj = 0; jj < 8; jj++)
        acc[ii][jj] = fmaf(av[ii], wv[jj], acc[ii][jj]);
  }
  const int e  = e0 + et;          // multiple of 8, stays inside one 64-block
  const int kc = e >> 6, d0 = e & 63;
  #pragma unroll
  for (int ii = 0; ii < 4; ii++) {
    const int bb = b0 + bt + ii;
    float* dst = hat + (((size_t)bb * NI_SZ + kc) * S_SZ + s) * D_SZ + d0;
    *(float4*)(dst)     = make_float4(acc[ii][0], acc[ii][1], acc[ii][2], acc[ii][3]);
    *(float4*)(dst + 4) = make_float4(acc[ii][4], acc[ii][5], acc[ii][6], acc[ii][7]);
  }
}

// ---------------- K4: dynamic routing, 1 block per b, wave = capsule, lane = d ----------------
__global__ __launch_bounds__(256) void route_kernel(
    const float* __restrict__ hat, const float* __restrict__ mask,
    float* __restrict__ out)
{
  const int b = blockIdx.x;
  __shared__ float cwS[NI_SZ][S_SZ];
  __shared__ float swS[NI_SZ][S_SZ];
  __shared__ float Ms[S_SZ];
  const int t = threadIdx.x;
  const int w = t >> 6, lane = t & 63;
  if (t < S_SZ) {
    Ms[t] = mask[b * S_SZ + t];
    cwS[0][t] = 0.f; cwS[1][t] = 0.f; cwS[2][t] = 0.f; cwS[3][t] = 0.f;
  }
  __syncthreads();
  const float* hk = hat + ((size_t)b * NI_SZ + w) * S_SZ * D_SZ + lane;
  float c = 0.f;
  for (int iter = 0; iter < 3; ++iter) {
    if (t < S_SZ) {   // softmax over the 4 capsules at position t, then mask
      const float c0 = cwS[0][t], c1 = cwS[1][t], c2 = cwS[2][t], c3 = cwS[3][t];
      const float m  = fmaxf(fmaxf(c0, c1), fmaxf(c2, c3));
      const float e0 = __expf(c0 - m), e1 = __expf(c1 - m),
                  e2 = __expf(c2 - m), e3 = __expf(c3 - m);
      float inv = 1.f / (e0 + e1 + e2 + e3);
      if (Ms[t] == 0.f) inv = 0.f;
      swS[0][t] = e0 * inv; swS[1][t] = e1 * inv;
      swS[2][t] = e2 * inv; swS[3][t] = e3 * inv;
    }
    __syncthreads();
    c = 0.f;
    #pragma unroll 4
    for (int s = 0; s < S_SZ; s++)
      c = fmaf(swS[w][s], hk[s * D_SZ], c);
    // squash
    float n = c * c;
    #pragma unroll
    for (int off = 32; off; off >>= 1) n += __shfl_xor(n, off);
    const float f = n / (1.f + n) * rsqrtf(n + 1e-9f);
    c *= f;
    if (iter < 2) {   // delta = hat . cap, cw += delta
      for (int s = 0; s < S_SZ; s++) {
        float p = c * hk[s * D_SZ];
        #pragma unroll
        for (int off = 32; off; off >>= 1) p += __shfl_xor(p, off);
        if (lane == 0) cwS[w][s] += p;
      }
    }
    __syncthreads();
  }
  out[((size_t)b * NI_SZ + w) * D_SZ + lane] = c;
}

extern "C" void kernel_launch(void* const* d_in, const int* in_sizes, int n_in,
                              void* d_out, int out_size, void* d_ws, size_t ws_size,
                              hipStream_t stream)
{
  const int*   uid     = (const int*)d_in[0];
  const int*   age     = (const int*)d_in[1];
  const int*   gender  = (const int*)d_in[2];
  const int*   occup   = (const int*)d_in[3];
  const int*   mid_his = (const int*)d_in[4];
  const float* mask    = (const float*)d_in[5];
  const float* U       = (const float*)d_in[6];
  const float* AT      = (const float*)d_in[7];
  const float* GT      = (const float*)d_in[8];
  const float* OT      = (const float*)d_in[9];
  const float* ME      = (const float*)d_in[10];
  const float* WC      = (const float*)d_in[11];

  float* out  = (float*)d_out;
  float* prof = (float*)d_ws;                         // 65,536 f
  float* item = prof + B_SZ * D_SZ;                   // 13,107,200 f
  float* hat  = item + (size_t)B_SZ * S_SZ * D_SZ;    // 52,428,800 f
  float* adj  = out + B_SZ * NI_SZ * D_SZ;            // output 1 region

  profile_kernel<<<B_SZ, 64, 0, stream>>>(uid, age, gender, occup, U, AT, GT, OT, prof);
  gather_kernel<<<(B_SZ * S_SZ * 16 + 255) / 256, 256, 0, stream>>>(mid_his, mask, ME, item);
  adj_kernel<<<B_SZ, 256, 0, stream>>>(item, prof, mask, adj);
  hat_kernel<<<dim3(S_SZ, 16, 2), 256, 0, stream>>>(item, WC, hat);
  route_kernel<<<B_SZ, 256, 0, stream>>>(hat, mask, out);
}

// Round 2
// 425.723 us; speedup vs baseline: 1.2887x; 1.2887x over previous
//
#include <hip/hip_runtime.h>

#define B_SZ 1024
#define S_SZ 200
#define D_SZ 64
#define NI_SZ 4
#define E_SZ 256

// ---------------- K1a: user profile = 0.25*(U[uid]+G[gender]+A[age]+O[occup]) ----------------
__global__ __launch_bounds__(64) void profile_kernel(
    const int* __restrict__ uid, const int* __restrict__ age,
    const int* __restrict__ gender, const int* __restrict__ occup,
    const float* __restrict__ U, const float* __restrict__ AT,
    const float* __restrict__ GT, const float* __restrict__ OT,
    float* __restrict__ prof)
{
  const int b = blockIdx.x;
  const int d = threadIdx.x;
  float v = U[(size_t)uid[b]   * D_SZ + d]
          + GT[(size_t)gender[b] * D_SZ + d]
          + AT[(size_t)age[b]    * D_SZ + d]
          + OT[(size_t)occup[b]  * D_SZ + d];
  prof[b * D_SZ + d] = 0.25f * v;
}

// ---------------- K1b: item_his = mid_emb[mid_his] * mask ----------------
__global__ __launch_bounds__(256) void gather_kernel(
    const int* __restrict__ mid_his, const float* __restrict__ mask,
    const float* __restrict__ memb, float* __restrict__ item)
{
  int idx = blockIdx.x * 256 + threadIdx.x;   // float4 units
  if (idx >= B_SZ * S_SZ * 16) return;
  const int d4 = (idx & 15) * 4;
  const int bs = idx >> 4;
  const float4 v = *(const float4*)(memb + (size_t)mid_his[bs] * D_SZ + d4);
  const float m = mask[bs];
  *(float4*)(item + (size_t)bs * D_SZ + d4) = make_float4(v.x*m, v.y*m, v.z*m, v.w*m);
}

// ---------------- K2: adj[b,i,j] = sigmoid(sum_d H[i,d]*P[d]*H[j,d]) * m_i * m_j ----------------
__global__ __launch_bounds__(256) void adj_kernel(
    const float* __restrict__ item, const float* __restrict__ prof,
    const float* __restrict__ mask, float* __restrict__ adj)
{
  const int b = blockIdx.x;
  __shared__ float HsT[D_SZ][208];   // [k][i], i<200, pad 208
  __shared__ float Ps[D_SZ];
  __shared__ float Ms[S_SZ];
  const float* Hg = item + (size_t)b * S_SZ * D_SZ;
  for (int idx = threadIdx.x; idx < S_SZ * 16; idx += 256) {
    const int i = idx >> 4, k4 = (idx & 15) * 4;
    const float4 v = *(const float4*)(Hg + i * D_SZ + k4);
    HsT[k4+0][i] = v.x; HsT[k4+1][i] = v.y;
    HsT[k4+2][i] = v.z; HsT[k4+3][i] = v.w;
  }
  if (threadIdx.x < D_SZ) Ps[threadIdx.x] = prof[b * D_SZ + threadIdx.x];
  if (threadIdx.x < S_SZ) Ms[threadIdx.x] = mask[b * S_SZ + threadIdx.x];
  __syncthreads();

  float* outb = adj + (size_t)b * S_SZ * S_SZ;
  for (int tile = threadIdx.x; tile < 625; tile += 256) {   // 25x25 tiles of 8x8
    const int ti = tile / 25, tj = tile % 25;
    const int i0 = ti * 8, j0 = tj * 8;
    float acc[8][8];
    #pragma unroll
    for (int ii = 0; ii < 8; ii++)
      #pragma unroll
      for (int jj = 0; jj < 8; jj++) acc[ii][jj] = 0.f;

    #pragma unroll 4
    for (int k = 0; k < D_SZ; k++) {
      const float pk = Ps[k];
      const float4 a0 = *(const float4*)&HsT[k][i0];
      const float4 a1 = *(const float4*)&HsT[k][i0 + 4];
      const float4 b0 = *(const float4*)&HsT[k][j0];
      const float4 b1 = *(const float4*)&HsT[k][j0 + 4];
      const float av[8] = {a0.x*pk, a0.y*pk, a0.z*pk, a0.w*pk,
                           a1.x*pk, a1.y*pk, a1.z*pk, a1.w*pk};
      const float bv[8] = {b0.x, b0.y, b0.z, b0.w, b1.x, b1.y, b1.z, b1.w};
      #pragma unroll
      for (int ii = 0; ii < 8; ii++)
        #pragma unroll
        for (int jj = 0; jj < 8; jj++)
          acc[ii][jj] = fmaf(av[ii], bv[jj], acc[ii][jj]);
    }
    #pragma unroll
    for (int ii = 0; ii < 8; ii++) {
      const float mi = Ms[i0 + ii];
      float r[8];
      #pragma unroll
      for (int jj = 0; jj < 8; jj++) {
        const float sg = 1.f / (1.f + __expf(-acc[ii][jj]));
        r[jj] = sg * mi * Ms[j0 + jj];
      }
      *(float4*)(outb + (i0+ii) * S_SZ + j0)     = make_float4(r[0], r[1], r[2], r[3]);
      *(float4*)(outb + (i0+ii) * S_SZ + j0 + 4) = make_float4(r[4], r[5], r[6], r[7]);
    }
  }
}

// ---------------- K3: hat[b,kc,s,d] = sum_k H[b,s,k] * W[s, kc*64+d, k] ----------------
__global__ __launch_bounds__(256) void hat_kernel(
    const float* __restrict__ item, const float* __restrict__ wcap,
    float* __restrict__ hat)
{
  const int s  = blockIdx.x;
  const int b0 = blockIdx.y * 64;
  const int e0 = blockIdx.z * 128;
  __shared__ float WsT[D_SZ][136];  // [k][e], e<128
  __shared__ float HsT[D_SZ][72];   // [k][b], b<64
  for (int idx = threadIdx.x; idx < 128 * 16; idx += 256) {
    const int e = idx >> 4, k4 = (idx & 15) * 4;
    const float4 v = *(const float4*)(wcap + ((size_t)s * E_SZ + e0 + e) * D_SZ + k4);
    WsT[k4+0][e] = v.x; WsT[k4+1][e] = v.y; WsT[k4+2][e] = v.z; WsT[k4+3][e] = v.w;
  }
  for (int idx = threadIdx.x; idx < 64 * 16; idx += 256) {
    const int r = idx >> 4, k4 = (idx & 15) * 4;
    const float4 v = *(const float4*)(item + ((size_t)(b0 + r) * S_SZ + s) * D_SZ + k4);
    HsT[k4+0][r] = v.x; HsT[k4+1][r] = v.y; HsT[k4+2][r] = v.z; HsT[k4+3][r] = v.w;
  }
  __syncthreads();

  const int ti = threadIdx.x >> 4;
  const int tj = threadIdx.x & 15;
  const int bt = ti * 4, et = tj * 8;
  float acc[4][8];
  #pragma unroll
  for (int ii = 0; ii < 4; ii++)
    #pragma unroll
    for (int jj = 0; jj < 8; jj++) acc[ii][jj] = 0.f;

  #pragma unroll 4
  for (int k = 0; k < D_SZ; k++) {
    const float4 a  = *(const float4*)&HsT[k][bt];
    const float4 w0 = *(const float4*)&WsT[k][et];
    const float4 w1 = *(const float4*)&WsT[k][et + 4];
    const float av[4] = {a.x, a.y, a.z, a.w};
    const float wv[8] = {w0.x, w0.y, w0.z, w0.w, w1.x, w1.y, w1.z, w1.w};
    #pragma unroll
    for (int ii = 0; ii < 4; ii++)
      #pragma unroll
      for (int jj = 0; jj < 8; jj++)
        acc[ii][jj] = fmaf(av[ii], wv[jj], acc[ii][jj]);
  }
  const int e  = e0 + et;
  const int kc = e >> 6, d0 = e & 63;
  #pragma unroll
  for (int ii = 0; ii < 4; ii++) {
    const int bb = b0 + bt + ii;
    float* dst = hat + (((size_t)bb * NI_SZ + kc) * S_SZ + s) * D_SZ + d0;
    *(float4*)(dst)     = make_float4(acc[ii][0], acc[ii][1], acc[ii][2], acc[ii][3]);
    *(float4*)(dst + 4) = make_float4(acc[ii][4], acc[ii][5], acc[ii][6], acc[ii][7]);
  }
}

// ---------------- K4: dynamic routing — hat slice register-resident, read ONCE ----------------
// One block per b, 1024 threads = 16 waves. wave w -> (capsule k = w>>2, s-quarter q = w&3).
// lane = d. Each lane holds hr[50] = hat[b,k,q*50+j,lane].
__global__ __launch_bounds__(1024) void route_kernel(
    const float* __restrict__ hat, const float* __restrict__ mask,
    float* __restrict__ out)
{
  const int b = blockIdx.x;
  const int t = threadIdx.x;
  const int w = t >> 6, lane = t & 63;
  const int k = w >> 2, q = w & 3;
  __shared__ float cwS[NI_SZ][S_SZ];
  __shared__ float swS[NI_SZ][S_SZ];
  __shared__ float capS[NI_SZ][D_SZ];
  __shared__ float partS[NI_SZ][4][D_SZ];
  __shared__ float Ms[S_SZ];

  if (t < S_SZ) {
    Ms[t] = mask[b * S_SZ + t];
    cwS[0][t] = 0.f; cwS[1][t] = 0.f; cwS[2][t] = 0.f; cwS[3][t] = 0.f;
  }

  // one coalesced read of this block's hat slice into registers
  float hr[50];
  const float* hg = hat + (((size_t)b * NI_SZ + k) * S_SZ + q * 50) * D_SZ + lane;
  #pragma unroll
  for (int j = 0; j < 50; j++) hr[j] = hg[j * D_SZ];
  __syncthreads();

  for (int iter = 0; iter < 3; ++iter) {
    // softmax over the 4 capsules at each position, then mask
    if (t < S_SZ) {
      const float c0 = cwS[0][t], c1 = cwS[1][t], c2 = cwS[2][t], c3 = cwS[3][t];
      const float m  = fmaxf(fmaxf(c0, c1), fmaxf(c2, c3));
      const float e0 = __expf(c0 - m), e1 = __expf(c1 - m),
                  e2 = __expf(c2 - m), e3 = __expf(c3 - m);
      float inv = 1.f / (e0 + e1 + e2 + e3);
      if (Ms[t] == 0.f) inv = 0.f;
      swS[0][t] = e0 * inv; swS[1][t] = e1 * inv;
      swS[2][t] = e2 * inv; swS[3][t] = e3 * inv;
    }
    __syncthreads();

    // per-wave partial cap
    float c = 0.f;
    #pragma unroll
    for (int j = 0; j < 50; j++) c = fmaf(swS[k][q * 50 + j], hr[j], c);
    partS[k][q][lane] = c;
    __syncthreads();

    // cross-wave reduce + squash
    if (t < NI_SZ * D_SZ) {
      const int k2 = t >> 6;
      float cap = partS[k2][0][lane] + partS[k2][1][lane]
                + partS[k2][2][lane] + partS[k2][3][lane];
      float n = cap * cap;
      #pragma unroll
      for (int off = 32; off; off >>= 1) n += __shfl_xor(n, off);
      const float f = n / (1.f + n) * rsqrtf(n + 1e-9f);
      capS[k2][lane] = cap * f;
    }
    __syncthreads();

    if (iter < 2) {
      // delta[k,s] = <hat[k,s,:], cap[k,:]>; 50 independent reductions -> ILP
      const float capd = capS[k][lane];
      #pragma unroll
      for (int j = 0; j < 50; j++) {
        float p = hr[j] * capd;
        #pragma unroll
        for (int off = 32; off; off >>= 1) p += __shfl_xor(p, off);
        if (lane == 0) cwS[k][q * 50 + j] += p;
      }
      __syncthreads();
    }
  }
  if (t < NI_SZ * D_SZ)
    out[(size_t)b * NI_SZ * D_SZ + t] = capS[t >> 6][lane];
}

extern "C" void kernel_launch(void* const* d_in, const int* in_sizes, int n_in,
                              void* d_out, int out_size, void* d_ws, size_t ws_size,
                              hipStream_t stream)
{
  const int*   uid     = (const int*)d_in[0];
  const int*   age     = (const int*)d_in[1];
  const int*   gender  = (const int*)d_in[2];
  const int*   occup   = (const int*)d_in[3];
  const int*   mid_his = (const int*)d_in[4];
  const float* mask    = (const float*)d_in[5];
  const float* U       = (const float*)d_in[6];
  const float* AT      = (const float*)d_in[7];
  const float* GT      = (const float*)d_in[8];
  const float* OT      = (const float*)d_in[9];
  const float* ME      = (const float*)d_in[10];
  const float* WC      = (const float*)d_in[11];

  float* out  = (float*)d_out;
  float* prof = (float*)d_ws;                         // 65,536 f
  float* item = prof + B_SZ * D_SZ;                   // 13,107,200 f
  float* hat  = item + (size_t)B_SZ * S_SZ * D_SZ;    // 52,428,800 f
  float* adj  = out + B_SZ * NI_SZ * D_SZ;            // output 1 region

  profile_kernel<<<B_SZ, 64, 0, stream>>>(uid, age, gender, occup, U, AT, GT, OT, prof);
  gather_kernel<<<(B_SZ * S_SZ * 16 + 255) / 256, 256, 0, stream>>>(mid_his, mask, ME, item);
  adj_kernel<<<B_SZ, 256, 0, stream>>>(item, prof, mask, adj);
  hat_kernel<<<dim3(S_SZ, 16, 2), 256, 0, stream>>>(item, WC, hat);
  route_kernel<<<B_SZ, 1024, 0, stream>>>(hat, mask, out);
}

// Round 3
// 326.006 us; speedup vs baseline: 1.6829x; 1.3059x over previous
//
#include <hip/hip_runtime.h>

#define B_SZ 1024
#define S_SZ 200
#define D_SZ 64
#define NI_SZ 4
#define E_SZ 256

// ---------------- K1a: user profile = 0.25*(U[uid]+G[gender]+A[age]+O[occup]) ----------------
__global__ __launch_bounds__(64) void profile_kernel(
    const int* __restrict__ uid, const int* __restrict__ age,
    const int* __restrict__ gender, const int* __restrict__ occup,
    const float* __restrict__ U, const float* __restrict__ AT,
    const float* __restrict__ GT, const float* __restrict__ OT,
    float* __restrict__ prof)
{
  const int b = blockIdx.x;
  const int d = threadIdx.x;
  float v = U[(size_t)uid[b]   * D_SZ + d]
          + GT[(size_t)gender[b] * D_SZ + d]
          + AT[(size_t)age[b]    * D_SZ + d]
          + OT[(size_t)occup[b]  * D_SZ + d];
  prof[b * D_SZ + d] = 0.25f * v;
}

// ---------------- K1b: item_his = mid_emb[mid_his] * mask ----------------
__global__ __launch_bounds__(256) void gather_kernel(
    const int* __restrict__ mid_his, const float* __restrict__ mask,
    const float* __restrict__ memb, float* __restrict__ item)
{
  int idx = blockIdx.x * 256 + threadIdx.x;   // float4 units
  if (idx >= B_SZ * S_SZ * 16) return;
  const int d4 = (idx & 15) * 4;
  const int bs = idx >> 4;
  const float4 v = *(const float4*)(memb + (size_t)mid_his[bs] * D_SZ + d4);
  const float m = mask[bs];
  *(float4*)(item + (size_t)bs * D_SZ + d4) = make_float4(v.x*m, v.y*m, v.z*m, v.w*m);
}

// ---------------- K2: adj[b,i,j] = sigmoid(sum_d H[i,d]*P[d]*H[j,d]) * m_i * m_j ----------------
__global__ __launch_bounds__(256) void adj_kernel(
    const float* __restrict__ item, const float* __restrict__ prof,
    const float* __restrict__ mask, float* __restrict__ adj)
{
  const int b = blockIdx.x;
  __shared__ float HsT[D_SZ][208];   // [k][i], i<200, pad 208
  __shared__ float Ps[D_SZ];
  __shared__ float Ms[S_SZ];
  const float* Hg = item + (size_t)b * S_SZ * D_SZ;
  for (int idx = threadIdx.x; idx < S_SZ * 16; idx += 256) {
    const int i = idx >> 4, k4 = (idx & 15) * 4;
    const float4 v = *(const float4*)(Hg + i * D_SZ + k4);
    HsT[k4+0][i] = v.x; HsT[k4+1][i] = v.y;
    HsT[k4+2][i] = v.z; HsT[k4+3][i] = v.w;
  }
  if (threadIdx.x < D_SZ) Ps[threadIdx.x] = prof[b * D_SZ + threadIdx.x];
  if (threadIdx.x < S_SZ) Ms[threadIdx.x] = mask[b * S_SZ + threadIdx.x];
  __syncthreads();

  float* outb = adj + (size_t)b * S_SZ * S_SZ;
  for (int tile = threadIdx.x; tile < 625; tile += 256) {   // 25x25 tiles of 8x8
    const int ti = tile / 25, tj = tile % 25;
    const int i0 = ti * 8, j0 = tj * 8;
    float acc[8][8];
    #pragma unroll
    for (int ii = 0; ii < 8; ii++)
      #pragma unroll
      for (int jj = 0; jj < 8; jj++) acc[ii][jj] = 0.f;

    #pragma unroll 4
    for (int k = 0; k < D_SZ; k++) {
      const float pk = Ps[k];
      const float4 a0 = *(const float4*)&HsT[k][i0];
      const float4 a1 = *(const float4*)&HsT[k][i0 + 4];
      const float4 b0 = *(const float4*)&HsT[k][j0];
      const float4 b1 = *(const float4*)&HsT[k][j0 + 4];
      const float av[8] = {a0.x*pk, a0.y*pk, a0.z*pk, a0.w*pk,
                           a1.x*pk, a1.y*pk, a1.z*pk, a1.w*pk};
      const float bv[8] = {b0.x, b0.y, b0.z, b0.w, b1.x, b1.y, b1.z, b1.w};
      #pragma unroll
      for (int ii = 0; ii < 8; ii++)
        #pragma unroll
        for (int jj = 0; jj < 8; jj++)
          acc[ii][jj] = fmaf(av[ii], bv[jj], acc[ii][jj]);
    }
    #pragma unroll
    for (int ii = 0; ii < 8; ii++) {
      const float mi = Ms[i0 + ii];
      float r[8];
      #pragma unroll
      for (int jj = 0; jj < 8; jj++) {
        const float sg = 1.f / (1.f + __expf(-acc[ii][jj]));
        r[jj] = sg * mi * Ms[j0 + jj];
      }
      *(float4*)(outb + (i0+ii) * S_SZ + j0)     = make_float4(r[0], r[1], r[2], r[3]);
      *(float4*)(outb + (i0+ii) * S_SZ + j0 + 4) = make_float4(r[4], r[5], r[6], r[7]);
    }
  }
}

// ---------------- K3: hat[b,kc,s,d] = sum_k H[b,s,k] * W[s, kc*64+d, k] ----------------
__global__ __launch_bounds__(256) void hat_kernel(
    const float* __restrict__ item, const float* __restrict__ wcap,
    float* __restrict__ hat)
{
  const int s  = blockIdx.x;
  const int b0 = blockIdx.y * 64;
  const int e0 = blockIdx.z * 128;
  __shared__ float WsT[D_SZ][136];  // [k][e], e<128
  __shared__ float HsT[D_SZ][72];   // [k][b], b<64
  for (int idx = threadIdx.x; idx < 128 * 16; idx += 256) {
    const int e = idx >> 4, k4 = (idx & 15) * 4;
    const float4 v = *(const float4*)(wcap + ((size_t)s * E_SZ + e0 + e) * D_SZ + k4);
    WsT[k4+0][e] = v.x; WsT[k4+1][e] = v.y; WsT[k4+2][e] = v.z; WsT[k4+3][e] = v.w;
  }
  for (int idx = threadIdx.x; idx < 64 * 16; idx += 256) {
    const int r = idx >> 4, k4 = (idx & 15) * 4;
    const float4 v = *(const float4*)(item + ((size_t)(b0 + r) * S_SZ + s) * D_SZ + k4);
    HsT[k4+0][r] = v.x; HsT[k4+1][r] = v.y; HsT[k4+2][r] = v.z; HsT[k4+3][r] = v.w;
  }
  __syncthreads();

  const int ti = threadIdx.x >> 4;
  const int tj = threadIdx.x & 15;
  const int bt = ti * 4, et = tj * 8;
  float acc[4][8];
  #pragma unroll
  for (int ii = 0; ii < 4; ii++)
    #pragma unroll
    for (int jj = 0; jj < 8; jj++) acc[ii][jj] = 0.f;

  #pragma unroll 4
  for (int k = 0; k < D_SZ; k++) {
    const float4 a  = *(const float4*)&HsT[k][bt];
    const float4 w0 = *(const float4*)&WsT[k][et];
    const float4 w1 = *(const float4*)&WsT[k][et + 4];
    const float av[4] = {a.x, a.y, a.z, a.w};
    const float wv[8] = {w0.x, w0.y, w0.z, w0.w, w1.x, w1.y, w1.z, w1.w};
    #pragma unroll
    for (int ii = 0; ii < 4; ii++)
      #pragma unroll
      for (int jj = 0; jj < 8; jj++)
        acc[ii][jj] = fmaf(av[ii], wv[jj], acc[ii][jj]);
  }
  const int e  = e0 + et;
  const int kc = e >> 6, d0 = e & 63;
  #pragma unroll
  for (int ii = 0; ii < 4; ii++) {
    const int bb = b0 + bt + ii;
    float* dst = hat + (((size_t)bb * NI_SZ + kc) * S_SZ + s) * D_SZ + d0;
    *(float4*)(dst)     = make_float4(acc[ii][0], acc[ii][1], acc[ii][2], acc[ii][3]);
    *(float4*)(dst + 4) = make_float4(acc[ii][4], acc[ii][5], acc[ii][6], acc[ii][7]);
  }
}

// ---------------- K4: dynamic routing, hat register-resident (pinned), read ONCE ----------------
// Block per b, 1024 threads = 16 waves: wave w -> (capsule k = w>>2, quarter q = w&3), lane = d.
// hr[50] per lane. Delta uses a multi-value butterfly: 63 shfl for 64 cross-lane sums,
// lane l ends holding the sum for s-index brev6(l).
__device__ __forceinline__ float rlane(float v, int l) {
  return __int_as_float(__builtin_amdgcn_readlane(__float_as_int(v), l));
}

__global__ __launch_bounds__(1024, 4) void route_kernel(
    const float* __restrict__ hat, const float* __restrict__ mask,
    float* __restrict__ out)
{
  const int b = blockIdx.x;
  const int t = threadIdx.x;
  const int w = t >> 6, lane = t & 63;
  const int k = w >> 2, q = w & 3;
  __shared__ float cwS[NI_SZ][212];
  __shared__ float partS[NI_SZ][4][D_SZ];

  // per-lane own-position mask (lane j <-> s = q*50+j)
  const float msv = (lane < 50) ? mask[b * S_SZ + q * 50 + lane] : 0.f;

  // one coalesced read of this wave's hat slice into registers, pinned
  float hr[50];
  const float* hg = hat + (((size_t)b * NI_SZ + k) * S_SZ + q * 50) * D_SZ + lane;
  #pragma unroll
  for (int j = 0; j < 50; j++) hr[j] = hg[j * D_SZ];
  #pragma unroll
  for (int j = 0; j < 50; j++) asm volatile("" : "+v"(hr[j]));

  const int jj = __brev(lane) >> 26;   // 6-bit bit-reverse of lane

  for (int iter = 0; iter < 3; ++iter) {
    // ---- softmax over capsules at this lane's own s (iter 0: cw==0 -> uniform 0.25) ----
    float swv;
    if (iter == 0) {
      swv = 0.25f * msv;
    } else {
      const int sidx = q * 50 + (lane < 50 ? lane : 49);
      const float a0 = cwS[0][sidx], a1 = cwS[1][sidx],
                  a2 = cwS[2][sidx], a3 = cwS[3][sidx];
      const float mx = fmaxf(fmaxf(a0, a1), fmaxf(a2, a3));
      const float e0 = __expf(a0 - mx), e1 = __expf(a1 - mx),
                  e2 = __expf(a2 - mx), e3 = __expf(a3 - mx);
      const float ek = (k == 0) ? e0 : (k == 1) ? e1 : (k == 2) ? e2 : e3;
      const float inv = 1.f / (e0 + e1 + e2 + e3);
      swv = (msv == 0.f) ? 0.f : ek * inv;
    }

    // ---- partial cap: sum over this wave's 50 positions (sw broadcast via readlane) ----
    float c0 = 0.f, c1 = 0.f, c2 = 0.f, c3 = 0.f;
    #pragma unroll
    for (int j = 0; j < 48; j += 4) {
      c0 = fmaf(rlane(swv, j + 0), hr[j + 0], c0);
      c1 = fmaf(rlane(swv, j + 1), hr[j + 1], c1);
      c2 = fmaf(rlane(swv, j + 2), hr[j + 2], c2);
      c3 = fmaf(rlane(swv, j + 3), hr[j + 3], c3);
    }
    c0 = fmaf(rlane(swv, 48), hr[48], c0);
    c1 = fmaf(rlane(swv, 49), hr[49], c1);
    partS[k][q][lane] = (c0 + c2) + (c1 + c3);
    __syncthreads();

    // ---- cap = sum of quarters, squash (redundant per wave) ----
    const float cap = partS[k][0][lane] + partS[k][1][lane]
                    + partS[k][2][lane] + partS[k][3][lane];
    float n = cap * cap;
    #pragma unroll
    for (int off = 32; off; off >>= 1) n += __shfl_xor(n, off);
    const float f = n / (1.f + n) * rsqrtf(n + 1e-9f);
    const float capd = cap * f;

    if (iter < 2) {
      // ---- delta[k,s] = <hat[k,s,:], cap>: multi-value butterfly over lanes ----
      float p[32];
      {
        const int bit = lane & 1;
        #pragma unroll
        for (int j = 0; j < 32; j++) {
          const float lo = hr[j] * capd;
          const float hi = (j + 32 < 50) ? hr[j + 32] * capd : 0.f;
          const float send = bit ? lo : hi;
          const float keep = bit ? hi : lo;
          p[j] = keep + __shfl_xor(send, 1);
        }
      }
      #pragma unroll
      for (int r = 1; r < 6; r++) {          // dists 2,4,8,16,32; halves 16,8,4,2,1
        const int dist = 1 << r;
        const int half = 32 >> r;
        const int bit = (lane >> r) & 1;
        #pragma unroll
        for (int j = 0; j < 32; j++) {
          if (j < half) {
            const float send = bit ? p[j] : p[j + half];
            const float keep = bit ? p[j + half] : p[j];
            p[j] = keep + __shfl_xor(send, dist);
          }
        }
      }
      if (jj < 50) {
        if (iter == 0) cwS[k][q * 50 + jj] = p[0];
        else           cwS[k][q * 50 + jj] += p[0];
      }
      __syncthreads();
    } else if (q == 0) {
      out[((size_t)b * NI_SZ + k) * D_SZ + lane] = capd;
    }
  }
}

extern "C" void kernel_launch(void* const* d_in, const int* in_sizes, int n_in,
                              void* d_out, int out_size, void* d_ws, size_t ws_size,
                              hipStream_t stream)
{
  const int*   uid     = (const int*)d_in[0];
  const int*   age     = (const int*)d_in[1];
  const int*   gender  = (const int*)d_in[2];
  const int*   occup   = (const int*)d_in[3];
  const int*   mid_his = (const int*)d_in[4];
  const float* mask    = (const float*)d_in[5];
  const float* U       = (const float*)d_in[6];
  const float* AT      = (const float*)d_in[7];
  const float* GT      = (const float*)d_in[8];
  const float* OT      = (const float*)d_in[9];
  const float* ME      = (const float*)d_in[10];
  const float* WC      = (const float*)d_in[11];

  float* out  = (float*)d_out;
  float* prof = (float*)d_ws;                         // 65,536 f
  float* item = prof + B_SZ * D_SZ;                   // 13,107,200 f
  float* hat  = item + (size_t)B_SZ * S_SZ * D_SZ;    // 52,428,800 f
  float* adj  = out + B_SZ * NI_SZ * D_SZ;            // output 1 region

  profile_kernel<<<B_SZ, 64, 0, stream>>>(uid, age, gender, occup, U, AT, GT, OT, prof);
  gather_kernel<<<(B_SZ * S_SZ * 16 + 255) / 256, 256, 0, stream>>>(mid_his, mask, ME, item);
  adj_kernel<<<B_SZ, 256, 0, stream>>>(item, prof, mask, adj);
  hat_kernel<<<dim3(S_SZ, 16, 2), 256, 0, stream>>>(item, WC, hat);
  route_kernel<<<B_SZ, 1024, 0, stream>>>(hat, mask, out);
}

// Round 4
// 167.733 us; speedup vs baseline: 3.2708x; 1.9436x over previous
//
#include <hip/hip_runtime.h>

#define B_SZ 1024
#define S_SZ 200
#define D_SZ 64
#define NI_SZ 4
#define E_SZ 256

using u16 = unsigned short;
using u32 = unsigned int;
typedef short  sh8    __attribute__((ext_vector_type(8)));
typedef __bf16 bf16x8 __attribute__((ext_vector_type(8)));
typedef float  f32x4  __attribute__((ext_vector_type(4)));

__device__ __forceinline__ u16 f2bf(float x) {          // RNE f32 -> bf16 bits
  u32 u = __float_as_uint(x);
  u += 0x7FFFu + ((u >> 16) & 1u);
  return (u16)(u >> 16);
}
__device__ __forceinline__ float bf2f(u16 h) {
  return __uint_as_float(((u32)h) << 16);
}
// swizzled LDS tile access: row-major [R][64] bf16 (128 B rows), byte ^= (row&7)<<4
__device__ __forceinline__ bf16x8 ldsw(const u16* arr, int row, int kshort) {
  const int idx = row * 64 + (kshort ^ ((row & 7) << 3));
  return __builtin_bit_cast(bf16x8, *(const sh8*)(arr + idx));
}
__device__ __forceinline__ void stsw(u16* arr, int row, int c, sh8 v) {
  *(sh8*)(arr + row * 64 + 8 * (c ^ (row & 7))) = v;
}

// ---------------- K1a: user profile ----------------
__global__ __launch_bounds__(64) void profile_kernel(
    const int* __restrict__ uid, const int* __restrict__ age,
    const int* __restrict__ gender, const int* __restrict__ occup,
    const float* __restrict__ U, const float* __restrict__ AT,
    const float* __restrict__ GT, const float* __restrict__ OT,
    float* __restrict__ prof)
{
  const int b = blockIdx.x;
  const int d = threadIdx.x;
  float v = U[(size_t)uid[b]   * D_SZ + d]
          + GT[(size_t)gender[b] * D_SZ + d]
          + AT[(size_t)age[b]    * D_SZ + d]
          + OT[(size_t)occup[b]  * D_SZ + d];
  prof[b * D_SZ + d] = 0.25f * v;
}

// ---------------- K1b: w_capsule -> bf16 ----------------
__global__ __launch_bounds__(256) void wconv_kernel(
    const float* __restrict__ W, u16* __restrict__ Wb)
{
  const int idx = blockIdx.x * 256 + threadIdx.x;     // 8-float units
  if (idx >= S_SZ * E_SZ * D_SZ / 8) return;
  const float4 a = *(const float4*)(W + (size_t)idx * 8);
  const float4 b = *(const float4*)(W + (size_t)idx * 8 + 4);
  sh8 r;
  r[0] = (short)f2bf(a.x); r[1] = (short)f2bf(a.y);
  r[2] = (short)f2bf(a.z); r[3] = (short)f2bf(a.w);
  r[4] = (short)f2bf(b.x); r[5] = (short)f2bf(b.y);
  r[6] = (short)f2bf(b.z); r[7] = (short)f2bf(b.w);
  *(sh8*)(Wb + (size_t)idx * 8) = r;
}

// ---------------- K1c: item_bs[b][s][d] = bf16(mid_emb[mid_his]*mask) ----------------
__global__ __launch_bounds__(256) void gather_kernel(
    const int* __restrict__ mid_his, const float* __restrict__ mask,
    const float* __restrict__ memb, u16* __restrict__ item_bs)
{
  const int idx = blockIdx.x * 256 + threadIdx.x;     // 8-elem units
  if (idx >= B_SZ * S_SZ * 8) return;
  const int bs = idx >> 3, d0 = (idx & 7) * 8;
  const float m = mask[bs];
  const float* src = memb + (size_t)mid_his[bs] * D_SZ + d0;
  const float4 a = *(const float4*)(src);
  const float4 b = *(const float4*)(src + 4);
  sh8 r;
  r[0] = (short)f2bf(a.x * m); r[1] = (short)f2bf(a.y * m);
  r[2] = (short)f2bf(a.z * m); r[3] = (short)f2bf(a.w * m);
  r[4] = (short)f2bf(b.x * m); r[5] = (short)f2bf(b.y * m);
  r[6] = (short)f2bf(b.z * m); r[7] = (short)f2bf(b.w * m);
  *(sh8*)(item_bs + (size_t)bs * D_SZ + d0) = r;
}

// ---------------- K2: adj via MFMA ----------------
// adj[b,i,j] = sigmoid(sum_d hu[i,d]*item[j,d]) * m_i * m_j,  hu = item*prof
__global__ __launch_bounds__(256, 3) void adj_mfma(
    const u16* __restrict__ item_bs, const float* __restrict__ prof,
    const float* __restrict__ mask, float* __restrict__ adj)
{
  const int b = blockIdx.x;
  __shared__ u16 Hs[208 * 64];   // item tile (B-side)
  __shared__ u16 Us[208 * 64];   // hu tile   (A-side)
  __shared__ float Ms[208];
  const int tid = threadIdx.x;

  for (int idx = tid; idx < 208 * 8; idx += 256) {
    const int row = idx >> 3, c = idx & 7;
    sh8 v, h;
    if (row < S_SZ) {
      v = *(const sh8*)(item_bs + ((size_t)b * S_SZ + row) * D_SZ + c * 8);
      const float4 p0 = *(const float4*)(prof + b * D_SZ + c * 8);
      const float4 p1 = *(const float4*)(prof + b * D_SZ + c * 8 + 4);
      const float pv[8] = {p0.x, p0.y, p0.z, p0.w, p1.x, p1.y, p1.z, p1.w};
      #pragma unroll
      for (int j = 0; j < 8; j++)
        h[j] = (short)f2bf(bf2f((u16)v[j]) * pv[j]);
    } else {
      #pragma unroll
      for (int j = 0; j < 8; j++) { v[j] = 0; h[j] = 0; }
    }
    stsw(Hs, row, c, v);
    stsw(Us, row, c, h);
  }
  if (tid < 208) Ms[tid] = (tid < S_SZ) ? mask[b * S_SZ + tid] : 0.f;
  __syncthreads();

  const int w = tid >> 6, l = tid & 63;
  const int lr = l & 15, lg = l >> 4;
  float* outb = adj + (size_t)b * S_SZ * S_SZ;

  for (int mt = 0; mt < 13; mt++) {
    const int arow = mt * 16 + lr;
    const bf16x8 a0 = ldsw(Us, arow, lg * 8);
    const bf16x8 a1 = ldsw(Us, arow, 32 + lg * 8);
    for (int nt = w; nt < 13; nt += 4) {
      const int brow = nt * 16 + lr;
      const bf16x8 b0 = ldsw(Hs, brow, lg * 8);
      const bf16x8 b1 = ldsw(Hs, brow, 32 + lg * 8);
      f32x4 acc = {0.f, 0.f, 0.f, 0.f};
      acc = __builtin_amdgcn_mfma_f32_16x16x32_bf16(a0, b0, acc, 0, 0, 0);
      acc = __builtin_amdgcn_mfma_f32_16x16x32_bf16(a1, b1, acc, 0, 0, 0);
      const int n = nt * 16 + lr;
      const float mj = Ms[n];
      #pragma unroll
      for (int r = 0; r < 4; r++) {
        const int m = mt * 16 + lg * 4 + r;
        if (m < S_SZ && n < S_SZ) {
          const float sg = 1.f / (1.f + __expf(-acc[r]));
          outb[(size_t)m * S_SZ + n] = sg * Ms[m] * mj;
        }
      }
    }
  }
}

// ---------------- K3: hat via MFMA, bf16 output ----------------
// hat[b,kc,s,d] = sum_k item[b,s,k] * W[s, kc*64+d, k]
__global__ __launch_bounds__(256, 4) void hat_mfma(
    const u16* __restrict__ item_bs, const u16* __restrict__ Wb,
    u16* __restrict__ hatb)
{
  const int s  = blockIdx.x;
  const int b0 = blockIdx.y * 64;
  __shared__ u16 As[64 * 64];     // item rows (A-side), 8 KB
  __shared__ u16 Ws_[256 * 64];   // W[s] (B-side), 32 KB
  const int tid = threadIdx.x;

  for (int idx = tid; idx < 64 * 8; idx += 256) {
    const int row = idx >> 3, c = idx & 7;
    const sh8 v = *(const sh8*)(item_bs + ((size_t)(b0 + row) * S_SZ + s) * D_SZ + c * 8);
    stsw(As, row, c, v);
  }
  for (int idx = tid; idx < 256 * 8; idx += 256) {
    const int row = idx >> 3, c = idx & 7;
    const sh8 v = *(const sh8*)(Wb + ((size_t)s * E_SZ + row) * D_SZ + c * 8);
    stsw(Ws_, row, c, v);
  }
  __syncthreads();

  const int w = tid >> 6, l = tid & 63;
  const int lr = l & 15, lg = l >> 4;

  f32x4 acc[4][4];
  #pragma unroll
  for (int mt = 0; mt < 4; mt++)
    #pragma unroll
    for (int nt = 0; nt < 4; nt++) acc[mt][nt] = (f32x4){0.f, 0.f, 0.f, 0.f};

  #pragma unroll
  for (int ks = 0; ks < 2; ks++) {
    bf16x8 af[4], bf_[4];
    #pragma unroll
    for (int mt = 0; mt < 4; mt++)
      af[mt] = ldsw(As, mt * 16 + lr, ks * 32 + lg * 8);
    #pragma unroll
    for (int nt = 0; nt < 4; nt++)
      bf_[nt] = ldsw(Ws_, w * 64 + nt * 16 + lr, ks * 32 + lg * 8);
    #pragma unroll
    for (int mt = 0; mt < 4; mt++)
      #pragma unroll
      for (int nt = 0; nt < 4; nt++)
        acc[mt][nt] = __builtin_amdgcn_mfma_f32_16x16x32_bf16(af[mt], bf_[nt], acc[mt][nt], 0, 0, 0);
  }

  // e = w*64 + nt*16 + lr  ->  kc = w, d = nt*16 + lr
  #pragma unroll
  for (int mt = 0; mt < 4; mt++) {
    #pragma unroll
    for (int r = 0; r < 4; r++) {
      const int bb = b0 + mt * 16 + lg * 4 + r;
      u16* dst = hatb + (((size_t)bb * NI_SZ + w) * S_SZ + s) * D_SZ;
      #pragma unroll
      for (int nt = 0; nt < 4; nt++)
        dst[nt * 16 + lr] = f2bf(acc[mt][nt][r]);
    }
  }
}

// ---------------- K4: dynamic routing (bf16 hat, register-resident) ----------------
__device__ __forceinline__ float rlane(float v, int l) {
  return __int_as_float(__builtin_amdgcn_readlane(__float_as_int(v), l));
}

__global__ __launch_bounds__(1024, 4) void route_kernel(
    const u16* __restrict__ hatb, const float* __restrict__ mask,
    float* __restrict__ out)
{
  const int b = blockIdx.x;
  const int t = threadIdx.x;
  const int w = t >> 6, lane = t & 63;
  const int k = w >> 2, q = w & 3;
  __shared__ float cwS[NI_SZ][212];
  __shared__ float partS[NI_SZ][4][D_SZ];

  const float msv = (lane < 50) ? mask[b * S_SZ + q * 50 + lane] : 0.f;

  float hr[50];
  const u16* hg = hatb + (((size_t)b * NI_SZ + k) * S_SZ + q * 50) * D_SZ + lane;
  #pragma unroll
  for (int j = 0; j < 50; j++) hr[j] = bf2f(hg[j * D_SZ]);
  #pragma unroll
  for (int j = 0; j < 50; j++) asm volatile("" : "+v"(hr[j]));

  const int jj = __brev(lane) >> 26;

  for (int iter = 0; iter < 3; ++iter) {
    float swv;
    if (iter == 0) {
      swv = 0.25f * msv;
    } else {
      const int sidx = q * 50 + (lane < 50 ? lane : 49);
      const float a0 = cwS[0][sidx], a1 = cwS[1][sidx],
                  a2 = cwS[2][sidx], a3 = cwS[3][sidx];
      const float mx = fmaxf(fmaxf(a0, a1), fmaxf(a2, a3));
      const float e0 = __expf(a0 - mx), e1 = __expf(a1 - mx),
                  e2 = __expf(a2 - mx), e3 = __expf(a3 - mx);
      const float ek = (k == 0) ? e0 : (k == 1) ? e1 : (k == 2) ? e2 : e3;
      const float inv = 1.f / (e0 + e1 + e2 + e3);
      swv = (msv == 0.f) ? 0.f : ek * inv;
    }

    float c0 = 0.f, c1 = 0.f, c2 = 0.f, c3 = 0.f;
    #pragma unroll
    for (int j = 0; j < 48; j += 4) {
      c0 = fmaf(rlane(swv, j + 0), hr[j + 0], c0);
      c1 = fmaf(rlane(swv, j + 1), hr[j + 1], c1);
      c2 = fmaf(rlane(swv, j + 2), hr[j + 2], c2);
      c3 = fmaf(rlane(swv, j + 3), hr[j + 3], c3);
    }
    c0 = fmaf(rlane(swv, 48), hr[48], c0);
    c1 = fmaf(rlane(swv, 49), hr[49], c1);
    partS[k][q][lane] = (c0 + c2) + (c1 + c3);
    __syncthreads();

    const float cap = partS[k][0][lane] + partS[k][1][lane]
                    + partS[k][2][lane] + partS[k][3][lane];
    float n = cap * cap;
    #pragma unroll
    for (int off = 32; off; off >>= 1) n += __shfl_xor(n, off);
    const float f = n / (1.f + n) * rsqrtf(n + 1e-9f);
    const float capd = cap * f;

    if (iter < 2) {
      float p[32];
      {
        const int bit = lane & 1;
        #pragma unroll
        for (int j = 0; j < 32; j++) {
          const float lo = hr[j] * capd;
          const float hi = (j + 32 < 50) ? hr[j + 32] * capd : 0.f;
          const float send = bit ? lo : hi;
          const float keep = bit ? hi : lo;
          p[j] = keep + __shfl_xor(send, 1);
        }
      }
      #pragma unroll
      for (int r = 1; r < 6; r++) {
        const int dist = 1 << r;
        const int half = 32 >> r;
        const int bit = (lane >> r) & 1;
        #pragma unroll
        for (int j = 0; j < 32; j++) {
          if (j < half) {
            const float send = bit ? p[j] : p[j + half];
            const float keep = bit ? p[j + half] : p[j];
            p[j] = keep + __shfl_xor(send, dist);
          }
        }
      }
      if (jj < 50) {
        if (iter == 0) cwS[k][q * 50 + jj] = p[0];
        else           cwS[k][q * 50 + jj] += p[0];
      }
      __syncthreads();
    } else if (q == 0) {
      out[((size_t)b * NI_SZ + k) * D_SZ + lane] = capd;
    }
  }
}

extern "C" void kernel_launch(void* const* d_in, const int* in_sizes, int n_in,
                              void* d_out, int out_size, void* d_ws, size_t ws_size,
                              hipStream_t stream)
{
  const int*   uid     = (const int*)d_in[0];
  const int*   age     = (const int*)d_in[1];
  const int*   gender  = (const int*)d_in[2];
  const int*   occup   = (const int*)d_in[3];
  const int*   mid_his = (const int*)d_in[4];
  const float* mask    = (const float*)d_in[5];
  const float* U       = (const float*)d_in[6];
  const float* AT      = (const float*)d_in[7];
  const float* GT      = (const float*)d_in[8];
  const float* OT      = (const float*)d_in[9];
  const float* ME      = (const float*)d_in[10];
  const float* WC      = (const float*)d_in[11];

  float* out  = (float*)d_out;
  float* adj  = out + B_SZ * NI_SZ * D_SZ;

  char* ws = (char*)d_ws;
  float* prof    = (float*)ws;                                   // 256 KiB
  u16*   item_bs = (u16*)(ws + 262144);                          // 26.2 MB
  u16*   Wb      = (u16*)(ws + 262144 + 26214400);               // 6.55 MB
  u16*   hatb    = (u16*)(ws + 262144 + 26214400 + 6553600);     // 104.9 MB

  profile_kernel<<<B_SZ, 64, 0, stream>>>(uid, age, gender, occup, U, AT, GT, OT, prof);
  wconv_kernel<<<(S_SZ * E_SZ * D_SZ / 8 + 255) / 256, 256, 0, stream>>>(WC, Wb);
  gather_kernel<<<(B_SZ * S_SZ * 8 + 255) / 256, 256, 0, stream>>>(mid_his, mask, ME, item_bs);
  adj_mfma<<<B_SZ, 256, 0, stream>>>(item_bs, prof, mask, adj);
  hat_mfma<<<dim3(S_SZ, 16), 256, 0, stream>>>(item_bs, Wb, hatb);
  route_kernel<<<B_SZ, 1024, 0, stream>>>(hatb, mask, out);
}